// Round 1
// baseline (295.883 us; speedup 1.0000x reference)
//
#include <hip/hip_runtime.h>
#include <math.h>

namespace {

__device__ __forceinline__ float rcp_f(float x) { return __builtin_amdgcn_rcpf(x); }

// z/(exp(z)-1), with 1 - z/2 for |z| < 1e-4 (matches reference efun)
__device__ __forceinline__ float efun(float z) {
    float e = __expf(z);
    float big = z * rcp_f(e - 1.0f);
    float small = 1.0f - 0.5f * z;
    return (fabsf(z) < 1e-4f) ? small : big;
}

struct F5 { float dV, dn, dm, dh, dp; };

__device__ __forceinline__ F5 hh(float V, float n, float m, float h, float p, float I_in) {
    // VT = -60 folded into the offsets
    float a_n = 0.16f  * efun(-0.2f  * (V + 45.0f));           // 0.032/0.2
    float b_n = 0.5f   * __expf((V + 50.0f) * -0.025f);        // exp(-(V+50)/40)
    float a_m = 1.28f  * efun(-0.25f * (V + 47.0f));           // 0.32/0.25
    float b_m = 1.4f   * efun( 0.2f  * (V + 20.0f));           // 0.28/0.2
    float a_h = 0.128f * __expf((V + 43.0f) * (-1.0f / 18.0f));
    float b_h = 4.0f   * rcp_f(1.0f + __expf(-0.2f * (V + 20.0f)));

    float ekv = -107.0f - V;   // E_K - V
    float m3  = m * m * m;
    float n2  = n * n;

    F5 r;
    r.dV = 4.0f  * m3 * h * (53.0f - V)     // gbar_Na * m^3 * h * (E_Na - V)
         + 1.5f  * (n2 * n2) * ekv          // gbar_K * n^4 * (E_K - V)
         + 0.07f * p * ekv                  // gbar_M * p * (E_K - V)
         + 0.1f  * (-70.0f - V)             // g_leak * (E_leak - V)
         + I_in;                            // C_MEM = 1

    // dx = (a/(a+b) - x) * (a+b)  — same form as reference
    float sn = a_n + b_n; r.dn = (a_n * rcp_f(sn) - n) * sn;
    float sm = a_m + b_m; r.dm = (a_m * rcp_f(sm) - m) * sm;
    float sh = a_h + b_h; r.dh = (a_h * rcp_f(sh) - h) * sh;

    float v1   = V + 35.0f;
    float pinf = rcp_f(1.0f + __expf(-0.1f * v1));
    float itau = (3.3f * __expf(0.05f * v1) + __expf(-0.05f * v1)) * (1.0f / 600.0f);
    r.dp = (pinf - p) * itau;
    return r;
}

__global__ __launch_bounds__(256) void hh_kernel(
    const int* __restrict__ tptr,
    const float4* __restrict__ V4, const float4* __restrict__ n4,
    const float4* __restrict__ m4, const float4* __restrict__ h4,
    const float4* __restrict__ p4,
    float4* __restrict__ out4, int nb4, float i_in_level)
{
    int i = blockIdx.x * blockDim.x + threadIdx.x;
    if (i >= nb4) return;

    // I_in = level if (t > I_ON=0 and t < I_OFF=inf) else 0
    float t = (float)(*tptr);
    float I_in = (t > 0.0f) ? i_in_level : 0.0f;

    float4 V = V4[i], n = n4[i], m = m4[i], h = h4[i], p = p4[i];

    F5 a = hh(V.x, n.x, m.x, h.x, p.x, I_in);
    F5 b = hh(V.y, n.y, m.y, h.y, p.y, I_in);
    F5 c = hh(V.z, n.z, m.z, h.z, p.z, I_in);
    F5 d = hh(V.w, n.w, m.w, h.w, p.w, I_in);

    out4[i          ] = make_float4(a.dV, b.dV, c.dV, d.dV);
    out4[i +     nb4] = make_float4(a.dn, b.dn, c.dn, d.dn);
    out4[i + 2 * nb4] = make_float4(a.dm, b.dm, c.dm, d.dm);
    out4[i + 3 * nb4] = make_float4(a.dh, b.dh, c.dh, d.dh);
    out4[i + 4 * nb4] = make_float4(a.dp, b.dp, c.dp, d.dp);
}

} // anonymous namespace

extern "C" void kernel_launch(void* const* d_in, const int* in_sizes, int n_in,
                              void* d_out, int out_size, void* d_ws, size_t ws_size,
                              hipStream_t stream) {
    // setup_inputs order: t (int scalar), V, n, m, h, p  (each float32, B elems)
    const int*    t = (const int*)   d_in[0];
    const float4* V = (const float4*)d_in[1];
    const float4* n = (const float4*)d_in[2];
    const float4* m = (const float4*)d_in[3];
    const float4* h = (const float4*)d_in[4];
    const float4* p = (const float4*)d_in[5];

    int B   = in_sizes[1];     // 8388608, divisible by 4
    int nb4 = B / 4;

    // CURR_LEVEL / A_SOMA, A_SOMA = pi * (70e-4)^2
    float i_in = (float)(0.0005 / (3.141592653589793 * 70.0e-4 * 70.0e-4));

    int block = 256;
    int grid  = (nb4 + block - 1) / block;
    hh_kernel<<<grid, block, 0, stream>>>(t, V, n, m, h, p, (float4*)d_out, nb4, i_in);
}